// Round 2
// baseline (94.506 us; speedup 1.0000x reference)
//
#include <hip/hip_runtime.h>

// Problem: loss_separation — sum_{b, i != j} exp(-0.5 * ||kp[b,i] - kp[b,j]||)
// B=32, N=2048, fp32 in, scalar fp32 out.

#define BATCHES 32
#define NPTS 2048
#define I_CHUNK 256
#define J_CHUNK 512
#define THREADS 256

__global__ __launch_bounds__(THREADS)
void loss_sep_kernel(const float2* __restrict__ kp, float* __restrict__ out) {
    // gridDim.x = (NPTS/I_CHUNK) * (NPTS/J_CHUNK), gridDim.y = BATCHES
    const int b = blockIdx.y;
    const int tiles_j = NPTS / J_CHUNK;
    const int i0 = (blockIdx.x / tiles_j) * I_CHUNK;
    const int j0 = (blockIdx.x % tiles_j) * J_CHUNK;
    const int tid = threadIdx.x;

    __shared__ float2 kj[J_CHUNK];

    // Stage the j-chunk: 512 float2 = 4096 B; 256 threads x 16 B (float4), coalesced.
    {
        const float4* src = reinterpret_cast<const float4*>(kp + (size_t)b * NPTS + j0);
        float4* dst = reinterpret_cast<float4*>(kj);
        dst[tid] = src[tid];
    }

    const int i = i0 + tid;
    const float2 ki = kp[(size_t)b * NPTS + i];
    __syncthreads();

    float acc = 0.0f;
    #pragma unroll 8
    for (int j = 0; j < J_CHUNK; ++j) {
        const float2 kjv = kj[j];                 // wave-uniform LDS read (broadcast)
        const float dx = ki.x - kjv.x;
        const float dy = ki.y - kjv.y;
        const float d2 = dx * dx + dy * dy;
        const float s = __builtin_amdgcn_sqrtf(d2); // raw v_sqrt_f32
        acc += __expf(-0.5f * s);                  // v_exp_f32 path
    }
    // If this j-chunk contains the diagonal element, its term was exp(0) = 1 exactly.
    if (i >= j0 && i < j0 + J_CHUNK) acc -= 1.0f;

    // Wave-64 butterfly reduce
    #pragma unroll
    for (int off = 32; off > 0; off >>= 1)
        acc += __shfl_down(acc, off, 64);

    __shared__ float wave_part[THREADS / 64];
    if ((tid & 63) == 0) wave_part[tid >> 6] = acc;
    __syncthreads();

    if (tid == 0) {
        float total = 0.0f;
        #pragma unroll
        for (int w = 0; w < THREADS / 64; ++w) total += wave_part[w];
        atomicAdd(out, total);
    }
}

extern "C" void kernel_launch(void* const* d_in, const int* in_sizes, int n_in,
                              void* d_out, int out_size, void* d_ws, size_t ws_size,
                              hipStream_t stream) {
    const float2* kp = (const float2*)d_in[0];
    float* out = (float*)d_out;

    // d_out is poisoned 0xAA before every timed launch — zero it on-stream.
    hipMemsetAsync(out, 0, sizeof(float), stream);

    dim3 grid((NPTS / I_CHUNK) * (NPTS / J_CHUNK), BATCHES);
    loss_sep_kernel<<<grid, THREADS, 0, stream>>>(kp, out);
}